// Round 14
// baseline (198.712 us; speedup 1.0000x reference)
//
#include <hip/hip_runtime.h>
#include <hip/hip_bf16.h>
#include <math.h>

#define B_  2
#define S_  2048
#define H_  768
#define NH_ 12
#define HD_ 64
#define I_  1152
#define LOG2E 1.4426950408889634f
#define SCALE_L2E 0.18033688011112042f   // (1/8) * log2(e)
#define M0_ 24.0f                        // fixed softmax shift (scores bounded; masks via E)

typedef __bf16 bf16;
typedef __bf16 bf16x8 __attribute__((ext_vector_type(8)));
typedef float  f32x4  __attribute__((ext_vector_type(4)));
typedef float  f32x16 __attribute__((ext_vector_type(16)));
typedef float  f32x2  __attribute__((ext_vector_type(2)));
typedef unsigned u32x2 __attribute__((ext_vector_type(2)));
typedef unsigned u32x4 __attribute__((ext_vector_type(4)));

__device__ __forceinline__ void gll16(const void* g, void* l) {
  __builtin_amdgcn_global_load_lds((const __attribute__((address_space(1))) void*)g,
                                   (__attribute__((address_space(3))) void*)l, 16, 0, 0);
}

__device__ __forceinline__ unsigned pack_bf16(float a, float b) {
  union { bf16 e[2]; unsigned u; } r;
  r.e[0] = (bf16)a; r.e[1] = (bf16)b;
  return r.u;
}

__device__ __forceinline__ void plswap(unsigned &a, unsigned &b) {
  asm volatile("v_permlane32_swap_b32 %0, %1" : "+v"(a), "+v"(b));
}

#define CN1 442368   // 3*H*H/4
#define CN2 147456   // H*H/4
#define CN3 442368   // 2*I*H/4
#define CN4 221184   // H*I/4
#define MASK_BLKS 1024
#define CVT_BLKS  ((CN1 + CN2 + CN3 + CN4) / 256)   // 4896
#define ROPE_BLKS 1024                               // 8192*32/256
#define LN_BLKS   4096

// ---- prep: mask combine + weight cvt + rope table + LN1 in one launch ----
__global__ __launch_bounds__(256) void prep(
    const float* __restrict__ am, const float* __restrict__ swm,
    bf16* __restrict__ E, unsigned* __restrict__ flags,
    const float* __restrict__ qkvw, const float* __restrict__ ow,
    const float* __restrict__ wiw,  const float* __restrict__ wow,
    bf16* __restrict__ wqkv_b, bf16* __restrict__ wo_b,
    bf16* __restrict__ wwi_b,  bf16* __restrict__ wwo_b,
    f32x2* __restrict__ tbl,
    const float* __restrict__ hs, const float* __restrict__ anw,
    const float* __restrict__ anb, bf16* __restrict__ xln) {
  __shared__ float rs[4], rq[4];
  __shared__ unsigned shm[4];
  const int blk = blockIdx.x, tid = threadIdx.x;
  if (blk < MASK_BLKS) {
    const int kt = blk & 31, qi = (blk >> 5) & 15, bb = blk >> 9;
    float sm[8][4];
    bool ok = true;
#pragma unroll
    for (int c = 0; c < 8; ++c) {
      int idx4 = c * 256 + tid;
      int r = idx4 >> 4, col = (idx4 & 15) * 4;
      size_t g = ((size_t)(bb * S_) + qi * 128 + r) * S_ + kt * 64 + col;
      float4 x = *(const float4*)(am + g);
      float4 y = *(const float4*)(swm + g);
      sm[c][0] = x.x + y.x; sm[c][1] = x.y + y.y;
      sm[c][2] = x.z + y.z; sm[c][3] = x.w + y.w;
      ok = ok && (sm[c][0] == 0.f) && (sm[c][1] == 0.f) && (sm[c][2] == 0.f) && (sm[c][3] == 0.f);
    }
    unsigned long long bal = __ballot(ok);
    if ((tid & 63) == 0) shm[tid >> 6] = (bal == ~0ull) ? 1u : 0u;
    __syncthreads();
    unsigned flag = shm[0] & shm[1] & shm[2] & shm[3];
    if (tid == 0) flags[(bb * 16 + qi) * 32 + kt] = flag;
    if (!flag) {
#pragma unroll
      for (int c = 0; c < 8; ++c) {
        int idx4 = c * 256 + tid;
        int r = idx4 >> 4, col = (idx4 & 15) * 4;
        size_t g = ((size_t)(bb * S_) + qi * 128 + r) * S_ + kt * 64 + col;
        union { bf16 e[4]; uint2 u; } w;
        w.e[0] = (bf16)__expf(sm[c][0]); w.e[1] = (bf16)__expf(sm[c][1]);
        w.e[2] = (bf16)__expf(sm[c][2]); w.e[3] = (bf16)__expf(sm[c][3]);
        *(uint2*)(E + g) = w.u;
      }
    }
  } else if (blk < MASK_BLKS + CVT_BLKS) {
    int i = (blk - MASK_BLKS) * 256 + tid;
    const float* s; bf16* d; int o;
    if (i < CN1)                  { s = qkvw; d = wqkv_b; o = i; }
    else if (i < CN1 + CN2)       { s = ow;   d = wo_b;   o = i - CN1; }
    else if (i < CN1 + CN2 + CN3) { s = wiw;  d = wwi_b;  o = i - CN1 - CN2; }
    else                          { s = wow;  d = wwo_b;  o = i - CN1 - CN2 - CN3; }
    float4 v = ((const float4*)s)[o];
    union { bf16 e[4]; uint2 u; } r;
    r.e[0] = (bf16)v.x; r.e[1] = (bf16)v.y; r.e[2] = (bf16)v.z; r.e[3] = (bf16)v.w;
    ((uint2*)d)[o] = r.u;
  } else if (blk < MASK_BLKS + CVT_BLKS + ROPE_BLKS) {
    int i = (blk - MASK_BLKS - CVT_BLKS) * 256 + tid;
    int jp = i & 31, pos = i >> 5;
    float th = exp2f((float)jp * (-13.287712379549449f / 32.f));
    float sn, cs;
    sincosf((float)pos * th, &sn, &cs);
    tbl[i] = (f32x2){cs, sn};
  } else {
    int row = blk - MASK_BLKS - CVT_BLKS - ROPE_BLKS;
    const float* x = hs + (size_t)row * H_;
    float v0 = x[tid], v1 = x[tid + 256], v2 = x[tid + 512];
    float s = v0 + v1 + v2;
    float q = v0 * v0 + v1 * v1 + v2 * v2;
    for (int o = 1; o < 64; o <<= 1) { s += __shfl_xor(s, o); q += __shfl_xor(q, o); }
    if ((tid & 63) == 0) { rs[tid >> 6] = s; rq[tid >> 6] = q; }
    __syncthreads();
    s = rs[0] + rs[1] + rs[2] + rs[3];
    q = rq[0] + rq[1] + rq[2] + rq[3];
    float mu = s * (1.f / H_);
    float var = q * (1.f / H_) - mu * mu;
    float rstd = rsqrtf(var + 1e-5f);
    bf16* orow = xln + (size_t)row * H_;
    orow[tid]       = (bf16)((v0 - mu) * rstd * anw[tid]       + anb[tid]);
    orow[tid + 256] = (bf16)((v1 - mu) * rstd * anw[tid + 256] + anb[tid + 256]);
    orow[tid + 512] = (bf16)((v2 - mu) * rstd * anw[tid + 512] + anb[tid + 512]);
  }
}

// ---------------- LayerNorm (768) -> bf16 (LN2 standalone) ----------------
__global__ __launch_bounds__(256) void ln_bf16(const float* __restrict__ in,
                                               const float* __restrict__ w,
                                               const float* __restrict__ bia,
                                               bf16* __restrict__ out) {
  int row = blockIdx.x, tid = threadIdx.x;
  const float* x = in + (size_t)row * H_;
  float v0 = x[tid], v1 = x[tid + 256], v2 = x[tid + 512];
  float s = v0 + v1 + v2;
  float q = v0 * v0 + v1 * v1 + v2 * v2;
  for (int o = 1; o < 64; o <<= 1) { s += __shfl_xor(s, o); q += __shfl_xor(q, o); }
  __shared__ float rs[4], rq[4];
  if ((tid & 63) == 0) { rs[tid >> 6] = s; rq[tid >> 6] = q; }
  __syncthreads();
  s = rs[0] + rs[1] + rs[2] + rs[3];
  q = rq[0] + rq[1] + rq[2] + rq[3];
  float mu = s * (1.f / H_);
  float var = q * (1.f / H_) - mu * mu;
  float rstd = rsqrtf(var + 1e-5f);
  bf16* orow = out + (size_t)row * H_;
  orow[tid]       = (bf16)((v0 - mu) * rstd * w[tid]       + bia[tid]);
  orow[tid + 256] = (bf16)((v1 - mu) * rstd * w[tid + 256] + bia[tid + 256]);
  orow[tid + 512] = (bf16)((v2 - mu) * rstd * w[tid + 512] + bia[tid + 512]);
}

// -------- 2-phase double-buffered GEMM main loop (128x128 tile, BK=32) --------
__device__ __forceinline__ void gemm_main_loop(
    int K, const bf16* __restrict__ aSrc0, const bf16* __restrict__ aSrc1,
    const bf16* __restrict__ bSrc0, const bf16* __restrict__ bSrc1,
    bf16* As, bf16* Bs, int tid, int wr, int wc, int l15, int lg,
    f32x4 (&acc)[4][4]) {
  const int NT = K >> 5;
  auto stage = [&](int t, int buf) {
    const int ko = t * 32;
    bf16* ad = As + buf * 4096 + tid * 8;
    bf16* bd = Bs + buf * 4096 + tid * 8;
    gll16(aSrc0 + ko, ad);
    gll16(aSrc1 + ko, ad + 2048);
    gll16(bSrc0 + ko, bd);
    gll16(bSrc1 + ko, bd + 2048);
  };
  stage(0, 0);
  __syncthreads();
  for (int t = 0; t < NT; ++t) {
    const int cur = t & 1;
    if (t + 1 < NT) stage(t + 1, cur ^ 1);
    const bf16* Ab = As + cur * 4096;
    const bf16* Bb = Bs + cur * 4096;
    bf16x8 af[4], bfr[4];
#pragma unroll
    for (int i = 0; i < 4; ++i)
      af[i] = *(const bf16x8*)&Ab[(wr + i * 16 + l15) * 32 + lg * 8];
#pragma unroll
    for (int j = 0; j < 4; ++j)
      bfr[j] = *(const bf16x8*)&Bb[(wc + j * 16 + l15) * 32 + lg * 8];
    __builtin_amdgcn_s_setprio(1);
#pragma unroll
    for (int i = 0; i < 4; ++i)
#pragma unroll
      for (int j = 0; j < 4; ++j)
        acc[i][j] = __builtin_amdgcn_mfma_f32_16x16x32_bf16(af[i], bfr[j], acc[i][j], 0, 0, 0);
    __builtin_amdgcn_s_setprio(0);
    __syncthreads();
  }
}

// ---- 32x128-tile GEMM, dbuf 2-phase (skinny-N; grid = (N/128)x(M/32) = 3.0/CU) ----
template<bool BIAS, bool RES>
__global__ __launch_bounds__(256) void gemm32d(const bf16* __restrict__ A,
                                               const bf16* __restrict__ W,
                                               float* __restrict__ C,
                                               const float* __restrict__ bias,
                                               const float* __restrict__ res,
                                               int M, int N, int K) {
  __shared__ bf16 As[2 * 32 * 32];     // 4 KB
  __shared__ bf16 Bs[2 * 128 * 32];    // 16 KB
  const int tid = threadIdx.x, lane = tid & 63, wv = tid >> 6;
  const int bm = blockIdx.y * 32, bn = blockIdx.x * 128;
  const int wr = (wv >> 1) * 16, wc = (wv & 1) * 64;
  const int l15 = lane & 15, lg = lane >> 4;

  f32x4 acc[4] = {};
  const int srowB = tid >> 2, sccB = (tid & 3) * 8;
  const bf16* bSrc0 = W + (size_t)(bn + srowB) * K + sccB;
  const bf16* bSrc1 = W + (size_t)(bn + 64 + srowB) * K + sccB;
  const int srowA = tid >> 2;          // 0..31 for tid<128
  const bf16* aSrc = A + (size_t)(bm + (srowA & 31)) * K + sccB;

  const int NT = K >> 5;
  auto stage = [&](int t, int buf) {
    const int ko = t * 32;
    if (tid < 128)
      gll16(aSrc + ko, As + buf * 1024 + tid * 8);
    gll16(bSrc0 + ko, Bs + buf * 4096 + tid * 8);
    gll16(bSrc1 + ko, Bs + buf * 4096 + 2048 + tid * 8);
  };
  stage(0, 0);
  __syncthreads();
  for (int t = 0; t < NT; ++t) {
    const int cur = t & 1;
    if (t + 1 < NT) stage(t + 1, cur ^ 1);
    const bf16* Ab = As + cur * 1024;
    const bf16* Bb = Bs + cur * 4096;
    bf16x8 af, bfr[4];
    af = *(const bf16x8*)&Ab[(wr + l15) * 32 + lg * 8];
#pragma unroll
    for (int j = 0; j < 4; ++j)
      bfr[j] = *(const bf16x8*)&Bb[(wc + j * 16 + l15) * 32 + lg * 8];
    __builtin_amdgcn_s_setprio(1);
#pragma unroll
    for (int j = 0; j < 4; ++j)
      acc[j] = __builtin_amdgcn_mfma_f32_16x16x32_bf16(af, bfr[j], acc[j], 0, 0, 0);
    __builtin_amdgcn_s_setprio(0);
    __syncthreads();
  }

  const int r0 = lg * 4;
#pragma unroll
  for (int j = 0; j < 4; ++j) {
    int col = bn + wc + j * 16 + l15;
    float bv = BIAS ? bias[col] : 0.f;
#pragma unroll
    for (int r = 0; r < 4; ++r) {
      int row = bm + wr + r0 + r;
      float v = acc[j][r] + bv;
      if (RES) v += res[(size_t)row * N + col];
      C[(size_t)row * N + col] = v;
    }
  }
}

// ------- QKV GEMM with fused RoPE + split -> Q,K,V bf16 [B,NH,S,HD] -------
__global__ __launch_bounds__(256) void gemm_qkv(const bf16* __restrict__ A,
                                                const bf16* __restrict__ W,
                                                const int* __restrict__ pid,
                                                const f32x2* __restrict__ tbl,
                                                bf16* __restrict__ qb,
                                                bf16* __restrict__ kb,
                                                bf16* __restrict__ vb) {
  __shared__ bf16 As[2 * 128 * 32];
  __shared__ bf16 Bs[2 * 128 * 32];
  const int tid = threadIdx.x, lane = tid & 63, wv = tid >> 6;
  const int bm = blockIdx.y * 128, bn = blockIdx.x * 128;
  const int wr = (wv >> 1) * 64, wc = (wv & 1) * 64;
  const int l15 = lane & 15, lg = lane >> 4;
  const int K = H_;

  f32x4 acc[4][4] = {};
  const int srow = tid >> 2, scc = (tid & 3) * 8;
  gemm_main_loop(K,
      A + (size_t)(bm + srow) * K + scc, A + (size_t)(bm + 64 + srow) * K + scc,
      W + (size_t)(bn + srow) * K + scc, W + (size_t)(bn + 64 + srow) * K + scc,
      As, Bs, tid, wr, wc, l15, lg, acc);

  const int r0 = lg * 4;
  const int sect = bn / H_;                 // 0=q 1=k 2=v (block fully inside one)
  const int hcb = (bn % H_) + wc;
  bf16* dst0 = sect == 0 ? qb : (sect == 1 ? kb : vb);
#pragma unroll
  for (int i = 0; i < 4; ++i) {
#pragma unroll
    for (int r = 0; r < 4; ++r) {
      const int row = bm + wr + i * 16 + r0 + r;   // = b*2048 + s
      const int b = row >> 11, s = row & 2047;
      const int pos = (sect < 2) ? pid[row] : 0;
#pragma unroll
      for (int j = 0; j < 4; ++j) {
        const int hc = hcb + j * 16 + l15;
        const int h = hc >> 6, d = hc & 63;
        float x = acc[i][j][r];
        float v;
        if (sect < 2) {
          f32x2 cs = tbl[pos * 32 + (d >> 1)];
          float xp = __shfl_xor(x, 1);
          v = (d & 1) ? fmaf(x, cs.x, xp * cs.y) : fmaf(x, cs.x, -xp * cs.y);
        } else {
          v = x;
        }
        dst0[((size_t)(b * NH_ + h) * S_ + s) * HD_ + d] = (bf16)v;
      }
    }
  }
}

// ------- wi GEMM with fused bias + exact-GELU gate -> gated bf16 [rows, I] -------
__global__ __launch_bounds__(256) void gemm_wi(const bf16* __restrict__ A,
                                               const bf16* __restrict__ W,
                                               const float* __restrict__ bias,
                                               bf16* __restrict__ g) {
  __shared__ bf16 As[2 * 128 * 32];
  __shared__ bf16 Bs[2 * 128 * 32];
  const int tid = threadIdx.x, lane = tid & 63, wv = tid >> 6;
  const int bm = blockIdx.y * 128, bn = blockIdx.x * 128;
  const int wr = (wv >> 1) * 64, wc = (wv & 1) * 64;
  const int l15 = lane & 15, lg = lane >> 4;
  const int K = H_;

  f32x4 acc[4][4] = {};
  const int srow = tid >> 2, scc = (tid & 3) * 8;
  gemm_main_loop(K,
      A + (size_t)(bm + srow) * K + scc, A + (size_t)(bm + 64 + srow) * K + scc,
      W + (size_t)(bn + srow) * K + scc, W + (size_t)(bn + 64 + srow) * K + scc,
      As, Bs, tid, wr, wc, l15, lg, acc);

  const int r0 = lg * 4;
#pragma unroll
  for (int j = 0; j < 4; ++j) {
    const int col = bn + wc + j * 16 + l15;
    const float bv = bias[col];
#pragma unroll
    for (int i = 0; i < 4; ++i) {
#pragma unroll
      for (int r = 0; r < 4; ++r) {
        const int row = bm + wr + i * 16 + r0 + r;
        float x = acc[i][j][r] + bv;
        float gx = 0.5f * x * (1.f + erff(x * 0.70710678118654752f));
        float gp = __shfl_xor(gx, 1);
        if (!(l15 & 1))
          g[(size_t)row * I_ + (col >> 1)] = (bf16)(gx * gp);
      }
    }
  }
}

// ------- flash attention: QBLK=64, 4 waves (2 wq x 2 ks), grid 768 = 3 blocks/CU ----
// K single-buffered per parity in LDS (16KB), V double-buffered (32KB) -> 48KB.
// Fixed-shift softmax: P = exp2(s*SCALE - M0); masks applied multiplicatively via E.
__global__ __launch_bounds__(256, 3) void attn4L(
    const bf16* __restrict__ Q, const bf16* __restrict__ Kg, const bf16* __restrict__ Vg,
    const bf16* __restrict__ Eg, const unsigned* __restrict__ flags, bf16* __restrict__ ctx) {
  __shared__ bf16 Ks[2][64 * 64];      // [parity] 16KB, single-buffered
  __shared__ bf16 Vt[2][2][64 * 64];   // [dbuf][parity] 32KB
  const int tid = threadIdx.x, lane = tid & 63, wv = tid >> 6;   // 4 waves
  const int wq = wv & 1, ks = wv >> 1;
  const int qi = blockIdx.x, h = blockIdx.y, b = blockIdx.z;
  const int l31 = lane & 31, hi = lane >> 5, b4 = (lane >> 4) & 1;
  const size_t headbase = (size_t)(b * NH_ + h) * S_ * HD_;
  const bf16* kbase = Kg + headbase;
  const bf16* vbase = Vg + headbase;
  const unsigned* fptr = flags + (b * 16 + (qi >> 1)) * 32;
  const int kswz = (l31 & 7) << 4;
  const int qrow = qi * 64 + wq * 32 + l31;
  const bf16* Erow = Eg + (size_t)b * S_ * S_ + (size_t)qrow * S_;

  union { unsigned u[4]; bf16x8 v; } ones;
  ones.u[0] = ones.u[1] = ones.u[2] = ones.u[3] = 0x3F803F80u;

  // Q fragments (B-operand): lane owns q-row = qrow
  bf16x8 qf[4];
  {
    const bf16* qp = Q + headbase + (size_t)qrow * HD_;
#pragma unroll
    for (int kc = 0; kc < 4; ++kc)
      qf[kc] = *(const bf16x8*)(qp + kc * 16 + hi * 8);
  }

  auto stageK = [&](int t, int par) {
#pragma unroll
    for (int c = 0; c < 2; ++c) {
      int ch = c * 256 + tid, kr = ch >> 3, sl = ch & 7;
      gll16(kbase + (size_t)t * 64 * HD_ + kr * HD_ + (sl ^ (kr & 7)) * 8, &Ks[par][ch * 8]);
    }
  };
  auto stageV = [&](int t, int bs, int par) {
#pragma unroll
    for (int c = 0; c < 2; ++c) {
      int ch = c * 256 + tid;
      int p = ch >> 7, kr = (ch & 127) >> 1, hf = ch & 1;
      gll16(vbase + (size_t)t * 64 * HD_ + kr * HD_ + (p >> 1) * 32 + (p & 1) * 16 + hf * 8,
            &Vt[bs][par][ch * 8]);
    }
  };

  float l = 0.f;
  f32x16 oa[2] = {};

  stageK(0, 0); stageK(1, 1);
  stageV(0, 0, 0); stageV(1, 0, 1);
  unsigned fl = fptr[ks];
  __syncthreads();

  for (int R = 0; R < 16; ++R) {
    const int cur = R & 1;
    const int kt = 2 * R + ks;

    // ---- S^T = K · Q^T  (K from single-buffered LDS) ----
    f32x16 sv[2];
    __builtin_amdgcn_s_setprio(1);
#pragma unroll
    for (int kb = 0; kb < 2; ++kb) {
      f32x16 s = {};
#pragma unroll
      for (int kc = 0; kc < 4; ++kc) {
        const bf16x8 kf = *(const bf16x8*)((const char*)&Ks[ks][0] +
            ((kb * 32 + l31) * 128 + ((kc * 32 + hi * 16) ^ kswz)));
        s = __builtin_amdgcn_mfma_f32_32x32x16_bf16(kf, qf[kc], s, 0, 0, 0);
      }
      sv[kb] = s;
    }
    __builtin_amdgcn_s_setprio(0);

    // bar1: all waves done reading Ks -> safe to overwrite (cheap: no vmem pending)
    __syncthreads();

    unsigned flN = 1;
    if (R < 15) {
      flN = fptr[kt + 2];
      stageK(2 * R + 2, 0); stageK(2 * R + 3, 1);
      stageV(2 * R + 2, cur ^ 1, 0); stageV(2 * R + 3, cur ^ 1, 1);
    }

    // ---- fixed-shift softmax: P = exp2(s*SCALE - M0) ----
#pragma unroll
    for (int kb = 0; kb < 2; ++kb)
#pragma unroll
      for (int r2 = 0; r2 < 16; ++r2)
        sv[kb][r2] = exp2f(fmaf(sv[kb][r2], SCALE_L2E, -M0_));
    if (!fl) {
#pragma unroll
      for (int kb = 0; kb < 2; ++kb)
#pragma unroll
        for (int rq = 0; rq < 4; ++rq) {
          union { bf16 e[4]; u32x2 u; } eu;
          eu.u = *(const u32x2*)(Erow + (size_t)kt * 64 + kb * 32 + rq * 8 + hi * 4);
#pragma unroll
          for (int j = 0; j < 4; ++j)
            sv[kb][rq * 4 + j] *= (float)eu.e[j];
        }
    }

    // ---- P pack + cross-half exchange -> B-fragments ----
    unsigned pk[2][4][2];
#pragma unroll
    for (int kb = 0; kb < 2; ++kb)
#pragma unroll
      for (int rq = 0; rq < 4; ++rq)
#pragma unroll
        for (int dd = 0; dd < 2; ++dd)
          pk[kb][rq][dd] = pack_bf16(sv[kb][rq * 4 + dd * 2], sv[kb][rq * 4 + dd * 2 + 1]);
    union { u32x4 u; bf16x8 v; } pauv[4];
#pragma unroll
    for (int kc = 0; kc < 4; ++kc) {
      const int kb = kc >> 1, rb = (kc & 1) * 2;
      unsigned pa0[2], pa1[2];
#pragma unroll
      for (int dd = 0; dd < 2; ++dd) {
        unsigned A = pk[kb][rb][dd], Bv = pk[kb][rb + 1][dd];
        plswap(A, Bv);
        pa0[dd] = A; pa1[dd] = Bv;
      }
      pauv[kc].u = (u32x4){pa0[0], pa0[1], pa1[0], pa1[1]};
    }

    // ---- l-sum on the MFMA pipe ----
    {
      f32x16 ls = {};
#pragma unroll
      for (int kc = 0; kc < 4; ++kc)
        ls = __builtin_amdgcn_mfma_f32_32x32x16_bf16(ones.v, pauv[kc].v, ls, 0, 0, 0);
      l += ls[0];
    }

    // ---- PV: O^T += V^T · P^T ----
    const unsigned vlds = (unsigned)(size_t)&Vt[cur][ks][0] + b4 * 1920;
#pragma unroll
    for (int db = 0; db < 2; ++db) {
      u32x2 tr[4][2];
#pragma unroll
      for (int kc = 0; kc < 4; ++kc)
#pragma unroll
        for (int rd = 0; rd < 2; ++rd) {
          unsigned ad = vlds + (db * 4096 + kc * 512 + rd * 128);
          asm volatile("ds_read_b64_tr_b16 %0, %1 offset:0" : "=v"(tr[kc][rd]) : "v"(ad));
        }
      asm volatile("s_waitcnt lgkmcnt(0)" ::: "memory");
      __builtin_amdgcn_sched_barrier(0);
      __builtin_amdgcn_s_setprio(1);
#pragma unroll
      for (int kc = 0; kc < 4; ++kc) {
        union { u32x4 u; bf16x8 v; } vfu;
        vfu.u = (u32x4){tr[kc][0][0], tr[kc][0][1], tr[kc][1][0], tr[kc][1][1]};
        oa[db] = __builtin_amdgcn_mfma_f32_32x32x16_bf16(vfu.v, pauv[kc].v, oa[db], 0, 0, 0);
      }
      __builtin_amdgcn_s_setprio(0);
    }
    // bar2: drains this step's gll16s (next K + next V ready), orders V reuse
    __syncthreads();
    fl = flN;
  }

  // ---- merge the two kv-parity groups (shared fixed shift -> just sum), store ----
  float* KO = (float*)&Ks[0][0];                    // 16 KB (2 wq x 2048 floats)
  float* ML = (float*)&Vt[1][0][0];                 // 256 B (l exchange)
  char*  TR = (char*)&Vt[1][0][0] + 512;            // 8 KB transpose area [2][32][128B]
  if (ks == 1) {
#pragma unroll
    for (int db = 0; db < 2; ++db)
#pragma unroll
      for (int rq = 0; rq < 4; ++rq) {
        int q4 = (db * 4 + rq) ^ (l31 & 7);
        *(f32x4*)&KO[wq * 2048 + l31 * 64 + hi * 32 + q4 * 4] =
            (f32x4){oa[db][rq * 4], oa[db][rq * 4 + 1], oa[db][rq * 4 + 2], oa[db][rq * 4 + 3]};
      }
    if (hi == 0) ML[wq * 32 + l31] = l;
  }
  __syncthreads();
  if (ks == 0) {
    float l1 = ML[wq * 32 + l31];
    float inv = 1.f / (l + l1);
#pragma unroll
    for (int db = 0; db < 2; ++db)
#pragma unroll
      for (int rq = 0; rq < 4; ++rq) {
        int q4 = (db * 4 + rq) ^ (l31 & 7);
        f32x4 o1 = *(const f32x4*)&KO[wq * 2048 + l31 * 64 + hi * 32 + q4 * 4];
        float f0 = (oa[db][rq * 4 + 0] + o1[0]) * inv;
        float f1 = (oa[db][rq * 4 + 1] + o1[1]) * inv;
        float f2 = (oa[db][rq * 4 + 2] + o1[2]) * inv;
        float f3 = (oa[db][rq * 4 + 3] + o1[3]) * inv;
        u32x2 w = (u32x2){pack_bf16(f0, f1), pack_bf16(f2, f3)};
        *(u32x2*)(TR + wq * 4096 + l31 * 128 + ((db * 64 + rq * 16 + hi * 8) ^ kswz)) = w;
      }
  }
  __syncthreads();
#pragma unroll
  for (int c = 0; c < 2; ++c) {
    int ch = c * 256 + tid, q = ch >> 3, sl = ch & 7;
    u32x4 vv = *(const u32x4*)(TR + ((q >> 5) * 4096 + (q & 31) * 128 + ((sl ^ (q & 7)) * 16)));
    *(u32x4*)(ctx + ((size_t)(b * S_) + qi * 64 + q) * H_ + h * HD_ + sl * 8) = vv;
  }
}

// ---------------- host ----------------
extern "C" void kernel_launch(void* const* d_in, const int* in_sizes, int n_in,
                              void* d_out, int out_size, void* d_ws, size_t ws_size,
                              hipStream_t stream) {
  const float* hs   = (const float*)d_in[0];
  const float* am   = (const float*)d_in[1];
  const float* swm  = (const float*)d_in[2];
  const int*   pid  = (const int*)d_in[3];
  const float* qkvw = (const float*)d_in[4];
  const float* ow   = (const float*)d_in[5];
  const float* anw  = (const float*)d_in[6];
  const float* anb  = (const float*)d_in[7];
  const float* mnw  = (const float*)d_in[8];
  const float* mnb  = (const float*)d_in[9];
  const float* wiw  = (const float*)d_in[10];
  const float* wib  = (const float*)d_in[11];
  const float* wow  = (const float*)d_in[12];
  const float* wob  = (const float*)d_in[13];
  float* out = (float*)d_out;

  char* ws = (char*)d_ws;
  size_t off = 0;
  auto alloc = [&](size_t bytes) { void* p = ws + off; off += (bytes + 255) & ~255ull; return p; };

  bf16* wqkv_b = (bf16*)alloc((size_t)3 * H_ * H_ * 2);
  bf16* wo_b   = (bf16*)alloc((size_t)H_ * H_ * 2);
  bf16* wwi_b  = (bf16*)alloc((size_t)2 * I_ * H_ * 2);
  bf16* wwo_b  = (bf16*)alloc((size_t)H_ * I_ * 2);
  bf16* xln    = (bf16*)alloc((size_t)B_ * S_ * H_ * 2);
  bf16* qb     = (bf16*)alloc((size_t)B_ * NH_ * S_ * HD_ * 2);
  bf16* kb     = (bf16*)alloc((size_t)B_ * NH_ * S_ * HD_ * 2);
  bf16* vb     = (bf16*)alloc((size_t)B_ * NH_ * S_ * HD_ * 2);
  bf16* Eg     = (bf16*)alloc((size_t)B_ * S_ * S_ * 2);
  unsigned* flg= (unsigned*)alloc((size_t)B_ * 16 * 32 * 4);
  bf16* ctx    = (bf16*)alloc((size_t)B_ * S_ * H_ * 2);
  float* hid2  = (float*)alloc((size_t)B_ * S_ * H_ * 4);
  bf16* gated  = (bf16*)alloc((size_t)B_ * S_ * I_ * 2);
  f32x2* tbl   = (f32x2*)alloc((size_t)8192 * 32 * 8);
  (void)ws_size; (void)n_in; (void)in_sizes; (void)out_size;

  const int rows = B_ * S_;   // 4096

  prep<<<MASK_BLKS + CVT_BLKS + ROPE_BLKS + LN_BLKS, 256, 0, stream>>>(
      am, swm, Eg, flg,
      qkvw, ow, wiw, wow, wqkv_b, wo_b, wwi_b, wwo_b, tbl, hs, anw, anb, xln);
  gemm_qkv<<<dim3(3 * H_ / 128, rows / 128), 256, 0, stream>>>(
      xln, wqkv_b, pid, tbl, qb, kb, vb);
  attn4L<<<dim3(S_ / 64, NH_, B_), 256, 0, stream>>>(qb, kb, vb, Eg, flg, ctx);
  gemm32d<false, true><<<dim3(H_ / 128, rows / 32), 256, 0, stream>>>(
      ctx, wo_b, hid2, nullptr, hs, rows, H_, H_);
  ln_bf16<<<rows, 256, 0, stream>>>(hid2, mnw, mnb, xln);
  gemm_wi<<<dim3(2 * I_ / 128, rows / 128), 256, 0, stream>>>(xln, wwi_b, wib, gated);
  gemm32d<true, true><<<dim3(H_ / 128, rows / 32), 256, 0, stream>>>(
      gated, wwo_b, out, wob, hid2, rows, H_, I_);
}

// Round 15
// 195.212 us; speedup vs baseline: 1.0179x; 1.0179x over previous
//
#include <hip/hip_runtime.h>
#include <hip/hip_bf16.h>
#include <math.h>

#define B_  2
#define S_  2048
#define H_  768
#define NH_ 12
#define HD_ 64
#define I_  1152
#define LOG2E 1.4426950408889634f
#define SCALE_L2E 0.18033688011112042f   // (1/8) * log2(e)
#define M0_ 24.0f                        // fixed softmax shift (scores bounded; masks via E)

typedef __bf16 bf16;
typedef __bf16 bf16x8 __attribute__((ext_vector_type(8)));
typedef float  f32x4  __attribute__((ext_vector_type(4)));
typedef float  f32x16 __attribute__((ext_vector_type(16)));
typedef float  f32x2  __attribute__((ext_vector_type(2)));
typedef unsigned u32x2 __attribute__((ext_vector_type(2)));
typedef unsigned u32x4 __attribute__((ext_vector_type(4)));

__device__ __forceinline__ void gll16(const void* g, void* l) {
  __builtin_amdgcn_global_load_lds((const __attribute__((address_space(1))) void*)g,
                                   (__attribute__((address_space(3))) void*)l, 16, 0, 0);
}

__device__ __forceinline__ unsigned pack_bf16(float a, float b) {
  union { bf16 e[2]; unsigned u; } r;
  r.e[0] = (bf16)a; r.e[1] = (bf16)b;
  return r.u;
}

__device__ __forceinline__ void plswap(unsigned &a, unsigned &b) {
  asm volatile("v_permlane32_swap_b32 %0, %1" : "+v"(a), "+v"(b));
}

#define CN1 442368   // 3*H*H/4
#define CN2 147456   // H*H/4
#define CN3 442368   // 2*I*H/4
#define CN4 221184   // H*I/4
#define MASK_BLKS 1024
#define CVT_BLKS  ((CN1 + CN2 + CN3 + CN4) / 256)   // 4896
#define ROPE_BLKS 1024                               // 8192*32/256
#define LN_BLKS   4096

// ---- prep: mask combine + weight cvt + rope table + LN1 in one launch ----
__global__ __launch_bounds__(256) void prep(
    const float* __restrict__ am, const float* __restrict__ swm,
    bf16* __restrict__ E, unsigned* __restrict__ flags,
    const float* __restrict__ qkvw, const float* __restrict__ ow,
    const float* __restrict__ wiw,  const float* __restrict__ wow,
    bf16* __restrict__ wqkv_b, bf16* __restrict__ wo_b,
    bf16* __restrict__ wwi_b,  bf16* __restrict__ wwo_b,
    f32x2* __restrict__ tbl,
    const float* __restrict__ hs, const float* __restrict__ anw,
    const float* __restrict__ anb, bf16* __restrict__ xln) {
  __shared__ float rs[4], rq[4];
  __shared__ unsigned shm[4];
  const int blk = blockIdx.x, tid = threadIdx.x;
  if (blk < MASK_BLKS) {
    const int kt = blk & 31, qi = (blk >> 5) & 15, bb = blk >> 9;
    float sm[8][4];
    bool ok = true;
#pragma unroll
    for (int c = 0; c < 8; ++c) {
      int idx4 = c * 256 + tid;
      int r = idx4 >> 4, col = (idx4 & 15) * 4;
      size_t g = ((size_t)(bb * S_) + qi * 128 + r) * S_ + kt * 64 + col;
      float4 x = *(const float4*)(am + g);
      float4 y = *(const float4*)(swm + g);
      sm[c][0] = x.x + y.x; sm[c][1] = x.y + y.y;
      sm[c][2] = x.z + y.z; sm[c][3] = x.w + y.w;
      ok = ok && (sm[c][0] == 0.f) && (sm[c][1] == 0.f) && (sm[c][2] == 0.f) && (sm[c][3] == 0.f);
    }
    unsigned long long bal = __ballot(ok);
    if ((tid & 63) == 0) shm[tid >> 6] = (bal == ~0ull) ? 1u : 0u;
    __syncthreads();
    unsigned flag = shm[0] & shm[1] & shm[2] & shm[3];
    if (tid == 0) flags[(bb * 16 + qi) * 32 + kt] = flag;
    if (!flag) {
#pragma unroll
      for (int c = 0; c < 8; ++c) {
        int idx4 = c * 256 + tid;
        int r = idx4 >> 4, col = (idx4 & 15) * 4;
        size_t g = ((size_t)(bb * S_) + qi * 128 + r) * S_ + kt * 64 + col;
        union { bf16 e[4]; uint2 u; } w;
        w.e[0] = (bf16)__expf(sm[c][0]); w.e[1] = (bf16)__expf(sm[c][1]);
        w.e[2] = (bf16)__expf(sm[c][2]); w.e[3] = (bf16)__expf(sm[c][3]);
        *(uint2*)(E + g) = w.u;
      }
    }
  } else if (blk < MASK_BLKS + CVT_BLKS) {
    int i = (blk - MASK_BLKS) * 256 + tid;
    const float* s; bf16* d; int o;
    if (i < CN1)                  { s = qkvw; d = wqkv_b; o = i; }
    else if (i < CN1 + CN2)       { s = ow;   d = wo_b;   o = i - CN1; }
    else if (i < CN1 + CN2 + CN3) { s = wiw;  d = wwi_b;  o = i - CN1 - CN2; }
    else                          { s = wow;  d = wwo_b;  o = i - CN1 - CN2 - CN3; }
    float4 v = ((const float4*)s)[o];
    union { bf16 e[4]; uint2 u; } r;
    r.e[0] = (bf16)v.x; r.e[1] = (bf16)v.y; r.e[2] = (bf16)v.z; r.e[3] = (bf16)v.w;
    ((uint2*)d)[o] = r.u;
  } else if (blk < MASK_BLKS + CVT_BLKS + ROPE_BLKS) {
    int i = (blk - MASK_BLKS - CVT_BLKS) * 256 + tid;
    int jp = i & 31, pos = i >> 5;
    float th = exp2f((float)jp * (-13.287712379549449f / 32.f));
    float sn, cs;
    sincosf((float)pos * th, &sn, &cs);
    tbl[i] = (f32x2){cs, sn};
  } else {
    int row = blk - MASK_BLKS - CVT_BLKS - ROPE_BLKS;
    const float* x = hs + (size_t)row * H_;
    float v0 = x[tid], v1 = x[tid + 256], v2 = x[tid + 512];
    float s = v0 + v1 + v2;
    float q = v0 * v0 + v1 * v1 + v2 * v2;
    for (int o = 1; o < 64; o <<= 1) { s += __shfl_xor(s, o); q += __shfl_xor(q, o); }
    if ((tid & 63) == 0) { rs[tid >> 6] = s; rq[tid >> 6] = q; }
    __syncthreads();
    s = rs[0] + rs[1] + rs[2] + rs[3];
    q = rq[0] + rq[1] + rq[2] + rq[3];
    float mu = s * (1.f / H_);
    float var = q * (1.f / H_) - mu * mu;
    float rstd = rsqrtf(var + 1e-5f);
    bf16* orow = xln + (size_t)row * H_;
    orow[tid]       = (bf16)((v0 - mu) * rstd * anw[tid]       + anb[tid]);
    orow[tid + 256] = (bf16)((v1 - mu) * rstd * anw[tid + 256] + anb[tid + 256]);
    orow[tid + 512] = (bf16)((v2 - mu) * rstd * anw[tid + 512] + anb[tid + 512]);
  }
}

// ---------------- LayerNorm (768) -> bf16 (LN2 standalone) ----------------
__global__ __launch_bounds__(256) void ln_bf16(const float* __restrict__ in,
                                               const float* __restrict__ w,
                                               const float* __restrict__ bia,
                                               bf16* __restrict__ out) {
  int row = blockIdx.x, tid = threadIdx.x;
  const float* x = in + (size_t)row * H_;
  float v0 = x[tid], v1 = x[tid + 256], v2 = x[tid + 512];
  float s = v0 + v1 + v2;
  float q = v0 * v0 + v1 * v1 + v2 * v2;
  for (int o = 1; o < 64; o <<= 1) { s += __shfl_xor(s, o); q += __shfl_xor(q, o); }
  __shared__ float rs[4], rq[4];
  if ((tid & 63) == 0) { rs[tid >> 6] = s; rq[tid >> 6] = q; }
  __syncthreads();
  s = rs[0] + rs[1] + rs[2] + rs[3];
  q = rq[0] + rq[1] + rq[2] + rq[3];
  float mu = s * (1.f / H_);
  float var = q * (1.f / H_) - mu * mu;
  float rstd = rsqrtf(var + 1e-5f);
  bf16* orow = out + (size_t)row * H_;
  orow[tid]       = (bf16)((v0 - mu) * rstd * w[tid]       + bia[tid]);
  orow[tid + 256] = (bf16)((v1 - mu) * rstd * w[tid + 256] + bia[tid + 256]);
  orow[tid + 512] = (bf16)((v2 - mu) * rstd * w[tid + 512] + bia[tid + 512]);
}

// ---- 64x128-tile dbuf 2-phase main loop (24 KB LDS, 8 MFMA/K-step) ----
__device__ __forceinline__ void gemm_loop64(
    int K, const bf16* __restrict__ aSrc0,
    const bf16* __restrict__ bSrc0, const bf16* __restrict__ bSrc1,
    bf16* As, bf16* Bs, int tid, int wr, int wc, int l15, int lg,
    f32x4 (&acc)[2][4]) {
  const int NT = K >> 5;
  auto stage = [&](int t, int buf) {
    const int ko = t * 32;
    gll16(aSrc0 + ko, As + buf * 2048 + tid * 8);
    gll16(bSrc0 + ko, Bs + buf * 4096 + tid * 8);
    gll16(bSrc1 + ko, Bs + buf * 4096 + 2048 + tid * 8);
  };
  stage(0, 0);
  __syncthreads();
  for (int t = 0; t < NT; ++t) {
    const int cur = t & 1;
    if (t + 1 < NT) stage(t + 1, cur ^ 1);
    const bf16* Ab = As + cur * 2048;
    const bf16* Bb = Bs + cur * 4096;
    bf16x8 af[2], bfr[4];
#pragma unroll
    for (int i = 0; i < 2; ++i)
      af[i] = *(const bf16x8*)&Ab[(wr + i * 16 + l15) * 32 + lg * 8];
#pragma unroll
    for (int j = 0; j < 4; ++j)
      bfr[j] = *(const bf16x8*)&Bb[(wc + j * 16 + l15) * 32 + lg * 8];
    __builtin_amdgcn_s_setprio(1);
#pragma unroll
    for (int i = 0; i < 2; ++i)
#pragma unroll
      for (int j = 0; j < 4; ++j)
        acc[i][j] = __builtin_amdgcn_mfma_f32_16x16x32_bf16(af[i], bfr[j], acc[i][j], 0, 0, 0);
    __builtin_amdgcn_s_setprio(0);
    __syncthreads();
  }
}

// ---- 64x128-tile GEMM, fp32 out (+bias/+residual) ----
template<bool BIAS, bool RES>
__global__ __launch_bounds__(256) void gemm64d(const bf16* __restrict__ A,
                                               const bf16* __restrict__ W,
                                               float* __restrict__ C,
                                               const float* __restrict__ bias,
                                               const float* __restrict__ res,
                                               int M, int N, int K) {
  __shared__ bf16 As[2 * 64 * 32];
  __shared__ bf16 Bs[2 * 128 * 32];
  const int tid = threadIdx.x, lane = tid & 63, wv = tid >> 6;
  const int bm = blockIdx.y * 64, bn = blockIdx.x * 128;
  const int wr = (wv >> 1) * 32, wc = (wv & 1) * 64;
  const int l15 = lane & 15, lg = lane >> 4;

  f32x4 acc[2][4] = {};
  const int srow = tid >> 2, scc = (tid & 3) * 8;
  gemm_loop64(K, A + (size_t)(bm + srow) * K + scc,
      W + (size_t)(bn + srow) * K + scc, W + (size_t)(bn + 64 + srow) * K + scc,
      As, Bs, tid, wr, wc, l15, lg, acc);

  const int r0 = lg * 4;
#pragma unroll
  for (int i = 0; i < 2; ++i) {
#pragma unroll
    for (int j = 0; j < 4; ++j) {
      int col = bn + wc + j * 16 + l15;
      float bv = BIAS ? bias[col] : 0.f;
#pragma unroll
      for (int r = 0; r < 4; ++r) {
        int row = bm + wr + i * 16 + r0 + r;
        float v = acc[i][j][r] + bv;
        if (RES) v += res[(size_t)row * N + col];
        C[(size_t)row * N + col] = v;
      }
    }
  }
}

// ------- QKV GEMM (64x128 tile) with fused RoPE + split -> Q,K,V bf16 -------
__global__ __launch_bounds__(256) void gemm_qkv64(const bf16* __restrict__ A,
                                                  const bf16* __restrict__ W,
                                                  const int* __restrict__ pid,
                                                  const f32x2* __restrict__ tbl,
                                                  bf16* __restrict__ qb,
                                                  bf16* __restrict__ kb,
                                                  bf16* __restrict__ vb) {
  __shared__ bf16 As[2 * 64 * 32];
  __shared__ bf16 Bs[2 * 128 * 32];
  const int tid = threadIdx.x, lane = tid & 63, wv = tid >> 6;
  const int bm = blockIdx.y * 64, bn = blockIdx.x * 128;
  const int wr = (wv >> 1) * 32, wc = (wv & 1) * 64;
  const int l15 = lane & 15, lg = lane >> 4;
  const int K = H_;

  f32x4 acc[2][4] = {};
  const int srow = tid >> 2, scc = (tid & 3) * 8;
  gemm_loop64(K, A + (size_t)(bm + srow) * K + scc,
      W + (size_t)(bn + srow) * K + scc, W + (size_t)(bn + 64 + srow) * K + scc,
      As, Bs, tid, wr, wc, l15, lg, acc);

  const int r0 = lg * 4;
  const int sect = bn / H_;                 // 0=q 1=k 2=v (block fully inside one)
  const int hcb = (bn % H_) + wc;
  bf16* dst0 = sect == 0 ? qb : (sect == 1 ? kb : vb);
#pragma unroll
  for (int i = 0; i < 2; ++i) {
#pragma unroll
    for (int r = 0; r < 4; ++r) {
      const int row = bm + wr + i * 16 + r0 + r;   // = b*2048 + s
      const int b = row >> 11, s = row & 2047;
      const int pos = (sect < 2) ? pid[row] : 0;
#pragma unroll
      for (int j = 0; j < 4; ++j) {
        const int hc = hcb + j * 16 + l15;
        const int h = hc >> 6, d = hc & 63;
        float x = acc[i][j][r];
        float v;
        if (sect < 2) {
          f32x2 cs = tbl[pos * 32 + (d >> 1)];
          float xp = __shfl_xor(x, 1);
          v = (d & 1) ? fmaf(x, cs.x, xp * cs.y) : fmaf(x, cs.x, -xp * cs.y);
        } else {
          v = x;
        }
        dst0[((size_t)(b * NH_ + h) * S_ + s) * HD_ + d] = (bf16)v;
      }
    }
  }
}

// ------- wi GEMM (64x128 tile) with fused bias + exact-GELU gate -> bf16 -------
__global__ __launch_bounds__(256) void gemm_wi64(const bf16* __restrict__ A,
                                                 const bf16* __restrict__ W,
                                                 const float* __restrict__ bias,
                                                 bf16* __restrict__ g) {
  __shared__ bf16 As[2 * 64 * 32];
  __shared__ bf16 Bs[2 * 128 * 32];
  const int tid = threadIdx.x, lane = tid & 63, wv = tid >> 6;
  const int bm = blockIdx.y * 64, bn = blockIdx.x * 128;
  const int wr = (wv >> 1) * 32, wc = (wv & 1) * 64;
  const int l15 = lane & 15, lg = lane >> 4;
  const int K = H_;

  f32x4 acc[2][4] = {};
  const int srow = tid >> 2, scc = (tid & 3) * 8;
  gemm_loop64(K, A + (size_t)(bm + srow) * K + scc,
      W + (size_t)(bn + srow) * K + scc, W + (size_t)(bn + 64 + srow) * K + scc,
      As, Bs, tid, wr, wc, l15, lg, acc);

  const int r0 = lg * 4;
#pragma unroll
  for (int j = 0; j < 4; ++j) {
    const int col = bn + wc + j * 16 + l15;
    const float bv = bias[col];
#pragma unroll
    for (int i = 0; i < 2; ++i) {
#pragma unroll
      for (int r = 0; r < 4; ++r) {
        const int row = bm + wr + i * 16 + r0 + r;
        float x = acc[i][j][r] + bv;
        float gx = 0.5f * x * (1.f + erff(x * 0.70710678118654752f));
        float gp = __shfl_xor(gx, 1);
        if (!(l15 & 1))
          g[(size_t)row * I_ + (col >> 1)] = (bf16)(gx * gp);
      }
    }
  }
}

// ------- flash attention: QBLK=64, 4 waves (2 wq x 2 ks), grid 768 = 3 blocks/CU ----
// K single-buffered per parity in LDS (16KB), V double-buffered (32KB) -> 48KB.
// Fixed-shift softmax: P = exp2(s*SCALE - M0); masks applied multiplicatively via E.
__global__ __launch_bounds__(256, 3) void attn4L(
    const bf16* __restrict__ Q, const bf16* __restrict__ Kg, const bf16* __restrict__ Vg,
    const bf16* __restrict__ Eg, const unsigned* __restrict__ flags, bf16* __restrict__ ctx) {
  __shared__ bf16 Ks[2][64 * 64];      // [parity] 16KB, single-buffered
  __shared__ bf16 Vt[2][2][64 * 64];   // [dbuf][parity] 32KB
  const int tid = threadIdx.x, lane = tid & 63, wv = tid >> 6;   // 4 waves
  const int wq = wv & 1, ks = wv >> 1;
  const int qi = blockIdx.x, h = blockIdx.y, b = blockIdx.z;
  const int l31 = lane & 31, hi = lane >> 5, b4 = (lane >> 4) & 1;
  const size_t headbase = (size_t)(b * NH_ + h) * S_ * HD_;
  const bf16* kbase = Kg + headbase;
  const bf16* vbase = Vg + headbase;
  const unsigned* fptr = flags + (b * 16 + (qi >> 1)) * 32;
  const int kswz = (l31 & 7) << 4;
  const int qrow = qi * 64 + wq * 32 + l31;
  const bf16* Erow = Eg + (size_t)b * S_ * S_ + (size_t)qrow * S_;

  union { unsigned u[4]; bf16x8 v; } ones;
  ones.u[0] = ones.u[1] = ones.u[2] = ones.u[3] = 0x3F803F80u;

  // Q fragments (B-operand): lane owns q-row = qrow
  bf16x8 qf[4];
  {
    const bf16* qp = Q + headbase + (size_t)qrow * HD_;
#pragma unroll
    for (int kc = 0; kc < 4; ++kc)
      qf[kc] = *(const bf16x8*)(qp + kc * 16 + hi * 8);
  }

  auto stageK = [&](int t, int par) {
#pragma unroll
    for (int c = 0; c < 2; ++c) {
      int ch = c * 256 + tid, kr = ch >> 3, sl = ch & 7;
      gll16(kbase + (size_t)t * 64 * HD_ + kr * HD_ + (sl ^ (kr & 7)) * 8, &Ks[par][ch * 8]);
    }
  };
  auto stageV = [&](int t, int bs, int par) {
#pragma unroll
    for (int c = 0; c < 2; ++c) {
      int ch = c * 256 + tid;
      int p = ch >> 7, kr = (ch & 127) >> 1, hf = ch & 1;
      gll16(vbase + (size_t)t * 64 * HD_ + kr * HD_ + (p >> 1) * 32 + (p & 1) * 16 + hf * 8,
            &Vt[bs][par][ch * 8]);
    }
  };

  float l = 0.f;
  f32x16 oa[2] = {};

  stageK(0, 0); stageK(1, 1);
  stageV(0, 0, 0); stageV(1, 0, 1);
  unsigned fl = fptr[ks];
  __syncthreads();

  for (int R = 0; R < 16; ++R) {
    const int cur = R & 1;
    const int kt = 2 * R + ks;

    // ---- S^T = K · Q^T  (K from single-buffered LDS) ----
    f32x16 sv[2];
    __builtin_amdgcn_s_setprio(1);
#pragma unroll
    for (int kb = 0; kb < 2; ++kb) {
      f32x16 s = {};
#pragma unroll
      for (int kc = 0; kc < 4; ++kc) {
        const bf16x8 kf = *(const bf16x8*)((const char*)&Ks[ks][0] +
            ((kb * 32 + l31) * 128 + ((kc * 32 + hi * 16) ^ kswz)));
        s = __builtin_amdgcn_mfma_f32_32x32x16_bf16(kf, qf[kc], s, 0, 0, 0);
      }
      sv[kb] = s;
    }
    __builtin_amdgcn_s_setprio(0);

    // bar1: all waves done reading Ks -> safe to overwrite (cheap: no vmem pending)
    __syncthreads();

    unsigned flN = 1;
    if (R < 15) {
      flN = fptr[kt + 2];
      stageK(2 * R + 2, 0); stageK(2 * R + 3, 1);
      stageV(2 * R + 2, cur ^ 1, 0); stageV(2 * R + 3, cur ^ 1, 1);
    }

    // ---- fixed-shift softmax: P = exp2(s*SCALE - M0) ----
#pragma unroll
    for (int kb = 0; kb < 2; ++kb)
#pragma unroll
      for (int r2 = 0; r2 < 16; ++r2)
        sv[kb][r2] = exp2f(fmaf(sv[kb][r2], SCALE_L2E, -M0_));
    if (!fl) {
#pragma unroll
      for (int kb = 0; kb < 2; ++kb)
#pragma unroll
        for (int rq = 0; rq < 4; ++rq) {
          union { bf16 e[4]; u32x2 u; } eu;
          eu.u = *(const u32x2*)(Erow + (size_t)kt * 64 + kb * 32 + rq * 8 + hi * 4);
#pragma unroll
          for (int j = 0; j < 4; ++j)
            sv[kb][rq * 4 + j] *= (float)eu.e[j];
        }
    }

    // ---- P pack + cross-half exchange -> B-fragments ----
    unsigned pk[2][4][2];
#pragma unroll
    for (int kb = 0; kb < 2; ++kb)
#pragma unroll
      for (int rq = 0; rq < 4; ++rq)
#pragma unroll
        for (int dd = 0; dd < 2; ++dd)
          pk[kb][rq][dd] = pack_bf16(sv[kb][rq * 4 + dd * 2], sv[kb][rq * 4 + dd * 2 + 1]);
    union { u32x4 u; bf16x8 v; } pauv[4];
#pragma unroll
    for (int kc = 0; kc < 4; ++kc) {
      const int kb = kc >> 1, rb = (kc & 1) * 2;
      unsigned pa0[2], pa1[2];
#pragma unroll
      for (int dd = 0; dd < 2; ++dd) {
        unsigned A = pk[kb][rb][dd], Bv = pk[kb][rb + 1][dd];
        plswap(A, Bv);
        pa0[dd] = A; pa1[dd] = Bv;
      }
      pauv[kc].u = (u32x4){pa0[0], pa0[1], pa1[0], pa1[1]};
    }

    // ---- l-sum on the MFMA pipe ----
    {
      f32x16 ls = {};
#pragma unroll
      for (int kc = 0; kc < 4; ++kc)
        ls = __builtin_amdgcn_mfma_f32_32x32x16_bf16(ones.v, pauv[kc].v, ls, 0, 0, 0);
      l += ls[0];
    }

    // ---- PV: O^T += V^T · P^T ----
    const unsigned vlds = (unsigned)(size_t)&Vt[cur][ks][0] + b4 * 1920;
#pragma unroll
    for (int db = 0; db < 2; ++db) {
      u32x2 tr[4][2];
#pragma unroll
      for (int kc = 0; kc < 4; ++kc)
#pragma unroll
        for (int rd = 0; rd < 2; ++rd) {
          unsigned ad = vlds + (db * 4096 + kc * 512 + rd * 128);
          asm volatile("ds_read_b64_tr_b16 %0, %1 offset:0" : "=v"(tr[kc][rd]) : "v"(ad));
        }
      asm volatile("s_waitcnt lgkmcnt(0)" ::: "memory");
      __builtin_amdgcn_sched_barrier(0);
      __builtin_amdgcn_s_setprio(1);
#pragma unroll
      for (int kc = 0; kc < 4; ++kc) {
        union { u32x4 u; bf16x8 v; } vfu;
        vfu.u = (u32x4){tr[kc][0][0], tr[kc][0][1], tr[kc][1][0], tr[kc][1][1]};
        oa[db] = __builtin_amdgcn_mfma_f32_32x32x16_bf16(vfu.v, pauv[kc].v, oa[db], 0, 0, 0);
      }
      __builtin_amdgcn_s_setprio(0);
    }
    // bar2: drains this step's gll16s (next K + next V ready), orders V reuse
    __syncthreads();
    fl = flN;
  }

  // ---- merge the two kv-parity groups (shared fixed shift -> just sum), store ----
  float* KO = (float*)&Ks[0][0];                    // 16 KB (2 wq x 2048 floats)
  float* ML = (float*)&Vt[1][0][0];                 // 256 B (l exchange)
  char*  TR = (char*)&Vt[1][0][0] + 512;            // 8 KB transpose area [2][32][128B]
  if (ks == 1) {
#pragma unroll
    for (int db = 0; db < 2; ++db)
#pragma unroll
      for (int rq = 0; rq < 4; ++rq) {
        int q4 = (db * 4 + rq) ^ (l31 & 7);
        *(f32x4*)&KO[wq * 2048 + l31 * 64 + hi * 32 + q4 * 4] =
            (f32x4){oa[db][rq * 4], oa[db][rq * 4 + 1], oa[db][rq * 4 + 2], oa[db][rq * 4 + 3]};
      }
    if (hi == 0) ML[wq * 32 + l31] = l;
  }
  __syncthreads();
  if (ks == 0) {
    float l1 = ML[wq * 32 + l31];
    float inv = 1.f / (l + l1);
#pragma unroll
    for (int db = 0; db < 2; ++db)
#pragma unroll
      for (int rq = 0; rq < 4; ++rq) {
        int q4 = (db * 4 + rq) ^ (l31 & 7);
        f32x4 o1 = *(const f32x4*)&KO[wq * 2048 + l31 * 64 + hi * 32 + q4 * 4];
        float f0 = (oa[db][rq * 4 + 0] + o1[0]) * inv;
        float f1 = (oa[db][rq * 4 + 1] + o1[1]) * inv;
        float f2 = (oa[db][rq * 4 + 2] + o1[2]) * inv;
        float f3 = (oa[db][rq * 4 + 3] + o1[3]) * inv;
        u32x2 w = (u32x2){pack_bf16(f0, f1), pack_bf16(f2, f3)};
        *(u32x2*)(TR + wq * 4096 + l31 * 128 + ((db * 64 + rq * 16 + hi * 8) ^ kswz)) = w;
      }
  }
  __syncthreads();
#pragma unroll
  for (int c = 0; c < 2; ++c) {
    int ch = c * 256 + tid, q = ch >> 3, sl = ch & 7;
    u32x4 vv = *(const u32x4*)(TR + ((q >> 5) * 4096 + (q & 31) * 128 + ((sl ^ (q & 7)) * 16)));
    *(u32x4*)(ctx + ((size_t)(b * S_) + qi * 64 + q) * H_ + h * HD_ + sl * 8) = vv;
  }
}

// ---------------- host ----------------
extern "C" void kernel_launch(void* const* d_in, const int* in_sizes, int n_in,
                              void* d_out, int out_size, void* d_ws, size_t ws_size,
                              hipStream_t stream) {
  const float* hs   = (const float*)d_in[0];
  const float* am   = (const float*)d_in[1];
  const float* swm  = (const float*)d_in[2];
  const int*   pid  = (const int*)d_in[3];
  const float* qkvw = (const float*)d_in[4];
  const float* ow   = (const float*)d_in[5];
  const float* anw  = (const float*)d_in[6];
  const float* anb  = (const float*)d_in[7];
  const float* mnw  = (const float*)d_in[8];
  const float* mnb  = (const float*)d_in[9];
  const float* wiw  = (const float*)d_in[10];
  const float* wib  = (const float*)d_in[11];
  const float* wow  = (const float*)d_in[12];
  const float* wob  = (const float*)d_in[13];
  float* out = (float*)d_out;

  char* ws = (char*)d_ws;
  size_t off = 0;
  auto alloc = [&](size_t bytes) { void* p = ws + off; off += (bytes + 255) & ~255ull; return p; };

  bf16* wqkv_b = (bf16*)alloc((size_t)3 * H_ * H_ * 2);
  bf16* wo_b   = (bf16*)alloc((size_t)H_ * H_ * 2);
  bf16* wwi_b  = (bf16*)alloc((size_t)2 * I_ * H_ * 2);
  bf16* wwo_b  = (bf16*)alloc((size_t)H_ * I_ * 2);
  bf16* xln    = (bf16*)alloc((size_t)B_ * S_ * H_ * 2);
  bf16* qb     = (bf16*)alloc((size_t)B_ * NH_ * S_ * HD_ * 2);
  bf16* kb     = (bf16*)alloc((size_t)B_ * NH_ * S_ * HD_ * 2);
  bf16* vb     = (bf16*)alloc((size_t)B_ * NH_ * S_ * HD_ * 2);
  bf16* Eg     = (bf16*)alloc((size_t)B_ * S_ * S_ * 2);
  unsigned* flg= (unsigned*)alloc((size_t)B_ * 16 * 32 * 4);
  bf16* ctx    = (bf16*)alloc((size_t)B_ * S_ * H_ * 2);
  float* hid2  = (float*)alloc((size_t)B_ * S_ * H_ * 4);
  bf16* gated  = (bf16*)alloc((size_t)B_ * S_ * I_ * 2);
  f32x2* tbl   = (f32x2*)alloc((size_t)8192 * 32 * 8);
  (void)ws_size; (void)n_in; (void)in_sizes; (void)out_size;

  const int rows = B_ * S_;   // 4096

  prep<<<MASK_BLKS + CVT_BLKS + ROPE_BLKS + LN_BLKS, 256, 0, stream>>>(
      am, swm, Eg, flg,
      qkvw, ow, wiw, wow, wqkv_b, wo_b, wwi_b, wwo_b, tbl, hs, anw, anb, xln);
  gemm_qkv64<<<dim3(3 * H_ / 128, rows / 64), 256, 0, stream>>>(
      xln, wqkv_b, pid, tbl, qb, kb, vb);
  attn4L<<<dim3(S_ / 64, NH_, B_), 256, 0, stream>>>(qb, kb, vb, Eg, flg, ctx);
  gemm64d<false, true><<<dim3(H_ / 128, rows / 64), 256, 0, stream>>>(
      ctx, wo_b, hid2, nullptr, hs, rows, H_, H_);
  ln_bf16<<<rows, 256, 0, stream>>>(hid2, mnw, mnb, xln);
  gemm_wi64<<<dim3(2 * I_ / 128, rows / 64), 256, 0, stream>>>(xln, wwi_b, wib, gated);
  gemm64d<true, true><<<dim3(H_ / 128, rows / 64), 256, 0, stream>>>(
      gated, wwo_b, out, wob, hid2, rows, H_, I_);
}

// Round 16
// 193.153 us; speedup vs baseline: 1.0288x; 1.0107x over previous
//
#include <hip/hip_runtime.h>
#include <hip/hip_bf16.h>
#include <math.h>

#define B_  2
#define S_  2048
#define H_  768
#define NH_ 12
#define HD_ 64
#define I_  1152
#define LOG2E 1.4426950408889634f
#define SCALE_L2E 0.18033688011112042f   // (1/8) * log2(e)
#define M0_ 24.0f                        // fixed softmax shift (scores bounded; masks via E)

typedef __bf16 bf16;
typedef __bf16 bf16x8 __attribute__((ext_vector_type(8)));
typedef float  f32x4  __attribute__((ext_vector_type(4)));
typedef float  f32x16 __attribute__((ext_vector_type(16)));
typedef float  f32x2  __attribute__((ext_vector_type(2)));
typedef unsigned u32x2 __attribute__((ext_vector_type(2)));
typedef unsigned u32x4 __attribute__((ext_vector_type(4)));

__device__ __forceinline__ void gll16(const void* g, void* l) {
  __builtin_amdgcn_global_load_lds((const __attribute__((address_space(1))) void*)g,
                                   (__attribute__((address_space(3))) void*)l, 16, 0, 0);
}

__device__ __forceinline__ unsigned pack_bf16(float a, float b) {
  union { bf16 e[2]; unsigned u; } r;
  r.e[0] = (bf16)a; r.e[1] = (bf16)b;
  return r.u;
}

__device__ __forceinline__ void plswap(unsigned &a, unsigned &b) {
  asm volatile("v_permlane32_swap_b32 %0, %1" : "+v"(a), "+v"(b));
}

#define CN1 442368   // 3*H*H/4
#define CN2 147456   // H*H/4
#define CN3 442368   // 2*I*H/4
#define CN4 221184   // H*I/4
#define MASK_BLKS 1024
#define CVT_BLKS  ((CN1 + CN2 + CN3 + CN4) / 256)   // 4896
#define ROPE_BLKS 1024                               // 8192*32/256
#define LN_BLKS   4096

// ---- prep: mask combine + weight cvt + rope table + LN1 in one launch ----
__global__ __launch_bounds__(256) void prep(
    const float* __restrict__ am, const float* __restrict__ swm,
    bf16* __restrict__ E, unsigned* __restrict__ flags,
    const float* __restrict__ qkvw, const float* __restrict__ ow,
    const float* __restrict__ wiw,  const float* __restrict__ wow,
    bf16* __restrict__ wqkv_b, bf16* __restrict__ wo_b,
    bf16* __restrict__ wwi_b,  bf16* __restrict__ wwo_b,
    f32x2* __restrict__ tbl,
    const float* __restrict__ hs, const float* __restrict__ anw,
    const float* __restrict__ anb, bf16* __restrict__ xln) {
  __shared__ float rs[4], rq[4];
  __shared__ unsigned shm[4];
  const int blk = blockIdx.x, tid = threadIdx.x;
  if (blk < MASK_BLKS) {
    const int kt = blk & 31, qi = (blk >> 5) & 15, bb = blk >> 9;
    float sm[8][4];
    bool ok = true;
#pragma unroll
    for (int c = 0; c < 8; ++c) {
      int idx4 = c * 256 + tid;
      int r = idx4 >> 4, col = (idx4 & 15) * 4;
      size_t g = ((size_t)(bb * S_) + qi * 128 + r) * S_ + kt * 64 + col;
      float4 x = *(const float4*)(am + g);
      float4 y = *(const float4*)(swm + g);
      sm[c][0] = x.x + y.x; sm[c][1] = x.y + y.y;
      sm[c][2] = x.z + y.z; sm[c][3] = x.w + y.w;
      ok = ok && (sm[c][0] == 0.f) && (sm[c][1] == 0.f) && (sm[c][2] == 0.f) && (sm[c][3] == 0.f);
    }
    unsigned long long bal = __ballot(ok);
    if ((tid & 63) == 0) shm[tid >> 6] = (bal == ~0ull) ? 1u : 0u;
    __syncthreads();
    unsigned flag = shm[0] & shm[1] & shm[2] & shm[3];
    if (tid == 0) flags[(bb * 16 + qi) * 32 + kt] = flag;
    if (!flag) {
#pragma unroll
      for (int c = 0; c < 8; ++c) {
        int idx4 = c * 256 + tid;
        int r = idx4 >> 4, col = (idx4 & 15) * 4;
        size_t g = ((size_t)(bb * S_) + qi * 128 + r) * S_ + kt * 64 + col;
        union { bf16 e[4]; uint2 u; } w;
        w.e[0] = (bf16)__expf(sm[c][0]); w.e[1] = (bf16)__expf(sm[c][1]);
        w.e[2] = (bf16)__expf(sm[c][2]); w.e[3] = (bf16)__expf(sm[c][3]);
        *(uint2*)(E + g) = w.u;
      }
    }
  } else if (blk < MASK_BLKS + CVT_BLKS) {
    int i = (blk - MASK_BLKS) * 256 + tid;
    const float* s; bf16* d; int o;
    if (i < CN1)                  { s = qkvw; d = wqkv_b; o = i; }
    else if (i < CN1 + CN2)       { s = ow;   d = wo_b;   o = i - CN1; }
    else if (i < CN1 + CN2 + CN3) { s = wiw;  d = wwi_b;  o = i - CN1 - CN2; }
    else                          { s = wow;  d = wwo_b;  o = i - CN1 - CN2 - CN3; }
    float4 v = ((const float4*)s)[o];
    union { bf16 e[4]; uint2 u; } r;
    r.e[0] = (bf16)v.x; r.e[1] = (bf16)v.y; r.e[2] = (bf16)v.z; r.e[3] = (bf16)v.w;
    ((uint2*)d)[o] = r.u;
  } else if (blk < MASK_BLKS + CVT_BLKS + ROPE_BLKS) {
    int i = (blk - MASK_BLKS - CVT_BLKS) * 256 + tid;
    int jp = i & 31, pos = i >> 5;
    float th = exp2f((float)jp * (-13.287712379549449f / 32.f));
    float sn, cs;
    sincosf((float)pos * th, &sn, &cs);
    tbl[i] = (f32x2){cs, sn};
  } else {
    int row = blk - MASK_BLKS - CVT_BLKS - ROPE_BLKS;
    const float* x = hs + (size_t)row * H_;
    float v0 = x[tid], v1 = x[tid + 256], v2 = x[tid + 512];
    float s = v0 + v1 + v2;
    float q = v0 * v0 + v1 * v1 + v2 * v2;
    for (int o = 1; o < 64; o <<= 1) { s += __shfl_xor(s, o); q += __shfl_xor(q, o); }
    if ((tid & 63) == 0) { rs[tid >> 6] = s; rq[tid >> 6] = q; }
    __syncthreads();
    s = rs[0] + rs[1] + rs[2] + rs[3];
    q = rq[0] + rq[1] + rq[2] + rq[3];
    float mu = s * (1.f / H_);
    float var = q * (1.f / H_) - mu * mu;
    float rstd = rsqrtf(var + 1e-5f);
    bf16* orow = xln + (size_t)row * H_;
    orow[tid]       = (bf16)((v0 - mu) * rstd * anw[tid]       + anb[tid]);
    orow[tid + 256] = (bf16)((v1 - mu) * rstd * anw[tid + 256] + anb[tid + 256]);
    orow[tid + 512] = (bf16)((v2 - mu) * rstd * anw[tid + 512] + anb[tid + 512]);
  }
}

// ---------------- LayerNorm (768) -> bf16 (LN2 standalone) ----------------
__global__ __launch_bounds__(256) void ln_bf16(const float* __restrict__ in,
                                               const float* __restrict__ w,
                                               const float* __restrict__ bia,
                                               bf16* __restrict__ out) {
  int row = blockIdx.x, tid = threadIdx.x;
  const float* x = in + (size_t)row * H_;
  float v0 = x[tid], v1 = x[tid + 256], v2 = x[tid + 512];
  float s = v0 + v1 + v2;
  float q = v0 * v0 + v1 * v1 + v2 * v2;
  for (int o = 1; o < 64; o <<= 1) { s += __shfl_xor(s, o); q += __shfl_xor(q, o); }
  __shared__ float rs[4], rq[4];
  if ((tid & 63) == 0) { rs[tid >> 6] = s; rq[tid >> 6] = q; }
  __syncthreads();
  s = rs[0] + rs[1] + rs[2] + rs[3];
  q = rq[0] + rq[1] + rq[2] + rq[3];
  float mu = s * (1.f / H_);
  float var = q * (1.f / H_) - mu * mu;
  float rstd = rsqrtf(var + 1e-5f);
  bf16* orow = out + (size_t)row * H_;
  orow[tid]       = (bf16)((v0 - mu) * rstd * w[tid]       + bia[tid]);
  orow[tid + 256] = (bf16)((v1 - mu) * rstd * w[tid + 256] + bia[tid + 256]);
  orow[tid + 512] = (bf16)((v2 - mu) * rstd * w[tid + 512] + bia[tid + 512]);
}

// ---- 64x128-tile dbuf 2-phase main loop, BK=32 (24 KB LDS, 8 MFMA/K-step) ----
__device__ __forceinline__ void gemm_loop64(
    int K, const bf16* __restrict__ aSrc0,
    const bf16* __restrict__ bSrc0, const bf16* __restrict__ bSrc1,
    bf16* As, bf16* Bs, int tid, int wr, int wc, int l15, int lg,
    f32x4 (&acc)[2][4]) {
  const int NT = K >> 5;
  auto stage = [&](int t, int buf) {
    const int ko = t * 32;
    gll16(aSrc0 + ko, As + buf * 2048 + tid * 8);
    gll16(bSrc0 + ko, Bs + buf * 4096 + tid * 8);
    gll16(bSrc1 + ko, Bs + buf * 4096 + 2048 + tid * 8);
  };
  stage(0, 0);
  __syncthreads();
  for (int t = 0; t < NT; ++t) {
    const int cur = t & 1;
    if (t + 1 < NT) stage(t + 1, cur ^ 1);
    const bf16* Ab = As + cur * 2048;
    const bf16* Bb = Bs + cur * 4096;
    bf16x8 af[2], bfr[4];
#pragma unroll
    for (int i = 0; i < 2; ++i)
      af[i] = *(const bf16x8*)&Ab[(wr + i * 16 + l15) * 32 + lg * 8];
#pragma unroll
    for (int j = 0; j < 4; ++j)
      bfr[j] = *(const bf16x8*)&Bb[(wc + j * 16 + l15) * 32 + lg * 8];
    __builtin_amdgcn_s_setprio(1);
#pragma unroll
    for (int i = 0; i < 2; ++i)
#pragma unroll
      for (int j = 0; j < 4; ++j)
        acc[i][j] = __builtin_amdgcn_mfma_f32_16x16x32_bf16(af[i], bfr[j], acc[i][j], 0, 0, 0);
    __builtin_amdgcn_s_setprio(0);
    __syncthreads();
  }
}

// ---- 64x128-tile GEMM, BK=64 dbuf (48 KB LDS, 16 MFMA/step, half the barriers) ----
// For the grid-384 skinny GEMMs where all blocks are co-resident and kernel time
// equals one block's serial path: halving the step count halves barrier drains.
template<bool BIAS, bool RES>
__global__ __launch_bounds__(256) void gemm64k(const bf16* __restrict__ A,
                                               const bf16* __restrict__ W,
                                               float* __restrict__ C,
                                               const float* __restrict__ bias,
                                               const float* __restrict__ res,
                                               int M, int N, int K) {
  __shared__ bf16 As[2 * 64 * 64];     // 16 KB: [buf][kk-half 2048][row 32-chunk]
  __shared__ bf16 Bs[2 * 128 * 64];    // 32 KB
  const int tid = threadIdx.x, lane = tid & 63, wv = tid >> 6;
  const int bm = blockIdx.y * 64, bn = blockIdx.x * 128;
  const int wr = (wv >> 1) * 32, wc = (wv & 1) * 64;
  const int l15 = lane & 15, lg = lane >> 4;

  f32x4 acc[2][4] = {};
  const int srow = tid >> 2, scc = (tid & 3) * 8;
  const bf16* aSrc = A + (size_t)(bm + srow) * K + scc;
  const bf16* bSrc0 = W + (size_t)(bn + srow) * K + scc;
  const bf16* bSrc1 = W + (size_t)(bn + 64 + srow) * K + scc;

  const int NT = K >> 6;               // BK=64 steps
  auto stage = [&](int t, int buf) {
    const int ko = t * 64;
    // half kk=0 (cols 0..31) and kk=1 (cols 32..63), each a [rows][32] panel
    gll16(aSrc + ko,        As + buf * 4096 + tid * 8);
    gll16(aSrc + ko + 32,   As + buf * 4096 + 2048 + tid * 8);
    gll16(bSrc0 + ko,       Bs + buf * 8192 + tid * 8);
    gll16(bSrc0 + ko + 32,  Bs + buf * 8192 + 4096 + tid * 8);
    gll16(bSrc1 + ko,       Bs + buf * 8192 + 2048 + tid * 8);
    gll16(bSrc1 + ko + 32,  Bs + buf * 8192 + 4096 + 2048 + tid * 8);
  };
  stage(0, 0);
  __syncthreads();
  for (int t = 0; t < NT; ++t) {
    const int cur = t & 1;
    if (t + 1 < NT) stage(t + 1, cur ^ 1);
#pragma unroll
    for (int kk = 0; kk < 2; ++kk) {
      const bf16* Ab = As + cur * 4096 + kk * 2048;
      const bf16* Bb = Bs + cur * 8192 + kk * 4096;
      bf16x8 af[2], bfr[4];
#pragma unroll
      for (int i = 0; i < 2; ++i)
        af[i] = *(const bf16x8*)&Ab[(wr + i * 16 + l15) * 32 + lg * 8];
#pragma unroll
      for (int j = 0; j < 4; ++j)
        bfr[j] = *(const bf16x8*)&Bb[(wc + j * 16 + l15) * 32 + lg * 8];
      __builtin_amdgcn_s_setprio(1);
#pragma unroll
      for (int i = 0; i < 2; ++i)
#pragma unroll
        for (int j = 0; j < 4; ++j)
          acc[i][j] = __builtin_amdgcn_mfma_f32_16x16x32_bf16(af[i], bfr[j], acc[i][j], 0, 0, 0);
      __builtin_amdgcn_s_setprio(0);
    }
    __syncthreads();
  }

  const int r0 = lg * 4;
#pragma unroll
  for (int i = 0; i < 2; ++i) {
#pragma unroll
    for (int j = 0; j < 4; ++j) {
      int col = bn + wc + j * 16 + l15;
      float bv = BIAS ? bias[col] : 0.f;
#pragma unroll
      for (int r = 0; r < 4; ++r) {
        int row = bm + wr + i * 16 + r0 + r;
        float v = acc[i][j][r] + bv;
        if (RES) v += res[(size_t)row * N + col];
        C[(size_t)row * N + col] = v;
      }
    }
  }
}

// ------- QKV GEMM (64x128 tile, BK=32) with fused RoPE + split -> Q,K,V bf16 -------
__global__ __launch_bounds__(256) void gemm_qkv64(const bf16* __restrict__ A,
                                                  const bf16* __restrict__ W,
                                                  const int* __restrict__ pid,
                                                  const f32x2* __restrict__ tbl,
                                                  bf16* __restrict__ qb,
                                                  bf16* __restrict__ kb,
                                                  bf16* __restrict__ vb) {
  __shared__ bf16 As[2 * 64 * 32];
  __shared__ bf16 Bs[2 * 128 * 32];
  const int tid = threadIdx.x, lane = tid & 63, wv = tid >> 6;
  const int bm = blockIdx.y * 64, bn = blockIdx.x * 128;
  const int wr = (wv >> 1) * 32, wc = (wv & 1) * 64;
  const int l15 = lane & 15, lg = lane >> 4;
  const int K = H_;

  f32x4 acc[2][4] = {};
  const int srow = tid >> 2, scc = (tid & 3) * 8;
  gemm_loop64(K, A + (size_t)(bm + srow) * K + scc,
      W + (size_t)(bn + srow) * K + scc, W + (size_t)(bn + 64 + srow) * K + scc,
      As, Bs, tid, wr, wc, l15, lg, acc);

  const int r0 = lg * 4;
  const int sect = bn / H_;                 // 0=q 1=k 2=v (block fully inside one)
  const int hcb = (bn % H_) + wc;
  bf16* dst0 = sect == 0 ? qb : (sect == 1 ? kb : vb);
#pragma unroll
  for (int i = 0; i < 2; ++i) {
#pragma unroll
    for (int r = 0; r < 4; ++r) {
      const int row = bm + wr + i * 16 + r0 + r;   // = b*2048 + s
      const int b = row >> 11, s = row & 2047;
      const int pos = (sect < 2) ? pid[row] : 0;
#pragma unroll
      for (int j = 0; j < 4; ++j) {
        const int hc = hcb + j * 16 + l15;
        const int h = hc >> 6, d = hc & 63;
        float x = acc[i][j][r];
        float v;
        if (sect < 2) {
          f32x2 cs = tbl[pos * 32 + (d >> 1)];
          float xp = __shfl_xor(x, 1);
          v = (d & 1) ? fmaf(x, cs.x, xp * cs.y) : fmaf(x, cs.x, -xp * cs.y);
        } else {
          v = x;
        }
        dst0[((size_t)(b * NH_ + h) * S_ + s) * HD_ + d] = (bf16)v;
      }
    }
  }
}

// ------- wi GEMM (64x128 tile, BK=32) with fused bias + exact-GELU gate -> bf16 -------
__global__ __launch_bounds__(256) void gemm_wi64(const bf16* __restrict__ A,
                                                 const bf16* __restrict__ W,
                                                 const float* __restrict__ bias,
                                                 bf16* __restrict__ g) {
  __shared__ bf16 As[2 * 64 * 32];
  __shared__ bf16 Bs[2 * 128 * 32];
  const int tid = threadIdx.x, lane = tid & 63, wv = tid >> 6;
  const int bm = blockIdx.y * 64, bn = blockIdx.x * 128;
  const int wr = (wv >> 1) * 32, wc = (wv & 1) * 64;
  const int l15 = lane & 15, lg = lane >> 4;
  const int K = H_;

  f32x4 acc[2][4] = {};
  const int srow = tid >> 2, scc = (tid & 3) * 8;
  gemm_loop64(K, A + (size_t)(bm + srow) * K + scc,
      W + (size_t)(bn + srow) * K + scc, W + (size_t)(bn + 64 + srow) * K + scc,
      As, Bs, tid, wr, wc, l15, lg, acc);

  const int r0 = lg * 4;
#pragma unroll
  for (int j = 0; j < 4; ++j) {
    const int col = bn + wc + j * 16 + l15;
    const float bv = bias[col];
#pragma unroll
    for (int i = 0; i < 2; ++i) {
#pragma unroll
      for (int r = 0; r < 4; ++r) {
        const int row = bm + wr + i * 16 + r0 + r;
        float x = acc[i][j][r] + bv;
        float gx = 0.5f * x * (1.f + erff(x * 0.70710678118654752f));
        float gp = __shfl_xor(gx, 1);
        if (!(l15 & 1))
          g[(size_t)row * I_ + (col >> 1)] = (bf16)(gx * gp);
      }
    }
  }
}

// ------- flash attention: QBLK=64, 4 waves (2 wq x 2 ks), grid 768 = 3 blocks/CU ----
// K single-buffered per parity in LDS (16KB), V double-buffered (32KB) -> 48KB.
// Fixed-shift softmax: P = exp2(s*SCALE - M0); masks applied multiplicatively via E.
__global__ __launch_bounds__(256, 3) void attn4L(
    const bf16* __restrict__ Q, const bf16* __restrict__ Kg, const bf16* __restrict__ Vg,
    const bf16* __restrict__ Eg, const unsigned* __restrict__ flags, bf16* __restrict__ ctx) {
  __shared__ bf16 Ks[2][64 * 64];      // [parity] 16KB, single-buffered
  __shared__ bf16 Vt[2][2][64 * 64];   // [dbuf][parity] 32KB
  const int tid = threadIdx.x, lane = tid & 63, wv = tid >> 6;   // 4 waves
  const int wq = wv & 1, ks = wv >> 1;
  const int qi = blockIdx.x, h = blockIdx.y, b = blockIdx.z;
  const int l31 = lane & 31, hi = lane >> 5, b4 = (lane >> 4) & 1;
  const size_t headbase = (size_t)(b * NH_ + h) * S_ * HD_;
  const bf16* kbase = Kg + headbase;
  const bf16* vbase = Vg + headbase;
  const unsigned* fptr = flags + (b * 16 + (qi >> 1)) * 32;
  const int kswz = (l31 & 7) << 4;
  const int qrow = qi * 64 + wq * 32 + l31;
  const bf16* Erow = Eg + (size_t)b * S_ * S_ + (size_t)qrow * S_;

  union { unsigned u[4]; bf16x8 v; } ones;
  ones.u[0] = ones.u[1] = ones.u[2] = ones.u[3] = 0x3F803F80u;

  // Q fragments (B-operand): lane owns q-row = qrow
  bf16x8 qf[4];
  {
    const bf16* qp = Q + headbase + (size_t)qrow * HD_;
#pragma unroll
    for (int kc = 0; kc < 4; ++kc)
      qf[kc] = *(const bf16x8*)(qp + kc * 16 + hi * 8);
  }

  auto stageK = [&](int t, int par) {
#pragma unroll
    for (int c = 0; c < 2; ++c) {
      int ch = c * 256 + tid, kr = ch >> 3, sl = ch & 7;
      gll16(kbase + (size_t)t * 64 * HD_ + kr * HD_ + (sl ^ (kr & 7)) * 8, &Ks[par][ch * 8]);
    }
  };
  auto stageV = [&](int t, int bs, int par) {
#pragma unroll
    for (int c = 0; c < 2; ++c) {
      int ch = c * 256 + tid;
      int p = ch >> 7, kr = (ch & 127) >> 1, hf = ch & 1;
      gll16(vbase + (size_t)t * 64 * HD_ + kr * HD_ + (p >> 1) * 32 + (p & 1) * 16 + hf * 8,
            &Vt[bs][par][ch * 8]);
    }
  };

  float l = 0.f;
  f32x16 oa[2] = {};

  stageK(0, 0); stageK(1, 1);
  stageV(0, 0, 0); stageV(1, 0, 1);
  unsigned fl = fptr[ks];
  __syncthreads();

  for (int R = 0; R < 16; ++R) {
    const int cur = R & 1;
    const int kt = 2 * R + ks;

    // ---- S^T = K · Q^T  (K from single-buffered LDS) ----
    f32x16 sv[2];
    __builtin_amdgcn_s_setprio(1);
#pragma unroll
    for (int kb = 0; kb < 2; ++kb) {
      f32x16 s = {};
#pragma unroll
      for (int kc = 0; kc < 4; ++kc) {
        const bf16x8 kf = *(const bf16x8*)((const char*)&Ks[ks][0] +
            ((kb * 32 + l31) * 128 + ((kc * 32 + hi * 16) ^ kswz)));
        s = __builtin_amdgcn_mfma_f32_32x32x16_bf16(kf, qf[kc], s, 0, 0, 0);
      }
      sv[kb] = s;
    }
    __builtin_amdgcn_s_setprio(0);

    // bar1: all waves done reading Ks -> safe to overwrite (cheap: no vmem pending)
    __syncthreads();

    unsigned flN = 1;
    if (R < 15) {
      flN = fptr[kt + 2];
      stageK(2 * R + 2, 0); stageK(2 * R + 3, 1);
      stageV(2 * R + 2, cur ^ 1, 0); stageV(2 * R + 3, cur ^ 1, 1);
    }

    // ---- fixed-shift softmax: P = exp2(s*SCALE - M0) ----
#pragma unroll
    for (int kb = 0; kb < 2; ++kb)
#pragma unroll
      for (int r2 = 0; r2 < 16; ++r2)
        sv[kb][r2] = exp2f(fmaf(sv[kb][r2], SCALE_L2E, -M0_));
    if (!fl) {
#pragma unroll
      for (int kb = 0; kb < 2; ++kb)
#pragma unroll
        for (int rq = 0; rq < 4; ++rq) {
          union { bf16 e[4]; u32x2 u; } eu;
          eu.u = *(const u32x2*)(Erow + (size_t)kt * 64 + kb * 32 + rq * 8 + hi * 4);
#pragma unroll
          for (int j = 0; j < 4; ++j)
            sv[kb][rq * 4 + j] *= (float)eu.e[j];
        }
    }

    // ---- P pack + cross-half exchange -> B-fragments ----
    unsigned pk[2][4][2];
#pragma unroll
    for (int kb = 0; kb < 2; ++kb)
#pragma unroll
      for (int rq = 0; rq < 4; ++rq)
#pragma unroll
        for (int dd = 0; dd < 2; ++dd)
          pk[kb][rq][dd] = pack_bf16(sv[kb][rq * 4 + dd * 2], sv[kb][rq * 4 + dd * 2 + 1]);
    union { u32x4 u; bf16x8 v; } pauv[4];
#pragma unroll
    for (int kc = 0; kc < 4; ++kc) {
      const int kb = kc >> 1, rb = (kc & 1) * 2;
      unsigned pa0[2], pa1[2];
#pragma unroll
      for (int dd = 0; dd < 2; ++dd) {
        unsigned A = pk[kb][rb][dd], Bv = pk[kb][rb + 1][dd];
        plswap(A, Bv);
        pa0[dd] = A; pa1[dd] = Bv;
      }
      pauv[kc].u = (u32x4){pa0[0], pa0[1], pa1[0], pa1[1]};
    }

    // ---- l-sum on the MFMA pipe ----
    {
      f32x16 ls = {};
#pragma unroll
      for (int kc = 0; kc < 4; ++kc)
        ls = __builtin_amdgcn_mfma_f32_32x32x16_bf16(ones.v, pauv[kc].v, ls, 0, 0, 0);
      l += ls[0];
    }

    // ---- PV: O^T += V^T · P^T ----
    const unsigned vlds = (unsigned)(size_t)&Vt[cur][ks][0] + b4 * 1920;
#pragma unroll
    for (int db = 0; db < 2; ++db) {
      u32x2 tr[4][2];
#pragma unroll
      for (int kc = 0; kc < 4; ++kc)
#pragma unroll
        for (int rd = 0; rd < 2; ++rd) {
          unsigned ad = vlds + (db * 4096 + kc * 512 + rd * 128);
          asm volatile("ds_read_b64_tr_b16 %0, %1 offset:0" : "=v"(tr[kc][rd]) : "v"(ad));
        }
      asm volatile("s_waitcnt lgkmcnt(0)" ::: "memory");
      __builtin_amdgcn_sched_barrier(0);
      __builtin_amdgcn_s_setprio(1);
#pragma unroll
      for (int kc = 0; kc < 4; ++kc) {
        union { u32x4 u; bf16x8 v; } vfu;
        vfu.u = (u32x4){tr[kc][0][0], tr[kc][0][1], tr[kc][1][0], tr[kc][1][1]};
        oa[db] = __builtin_amdgcn_mfma_f32_32x32x16_bf16(vfu.v, pauv[kc].v, oa[db], 0, 0, 0);
      }
      __builtin_amdgcn_s_setprio(0);
    }
    // bar2: drains this step's gll16s (next K + next V ready), orders V reuse
    __syncthreads();
    fl = flN;
  }

  // ---- merge the two kv-parity groups (shared fixed shift -> just sum), store ----
  float* KO = (float*)&Ks[0][0];                    // 16 KB (2 wq x 2048 floats)
  float* ML = (float*)&Vt[1][0][0];                 // 256 B (l exchange)
  char*  TR = (char*)&Vt[1][0][0] + 512;            // 8 KB transpose area [2][32][128B]
  if (ks == 1) {
#pragma unroll
    for (int db = 0; db < 2; ++db)
#pragma unroll
      for (int rq = 0; rq < 4; ++rq) {
        int q4 = (db * 4 + rq) ^ (l31 & 7);
        *(f32x4*)&KO[wq * 2048 + l31 * 64 + hi * 32 + q4 * 4] =
            (f32x4){oa[db][rq * 4], oa[db][rq * 4 + 1], oa[db][rq * 4 + 2], oa[db][rq * 4 + 3]};
      }
    if (hi == 0) ML[wq * 32 + l31] = l;
  }
  __syncthreads();
  if (ks == 0) {
    float l1 = ML[wq * 32 + l31];
    float inv = 1.f / (l + l1);
#pragma unroll
    for (int db = 0; db < 2; ++db)
#pragma unroll
      for (int rq = 0; rq < 4; ++rq) {
        int q4 = (db * 4 + rq) ^ (l31 & 7);
        f32x4 o1 = *(const f32x4*)&KO[wq * 2048 + l31 * 64 + hi * 32 + q4 * 4];
        float f0 = (oa[db][rq * 4 + 0] + o1[0]) * inv;
        float f1 = (oa[db][rq * 4 + 1] + o1[1]) * inv;
        float f2 = (oa[db][rq * 4 + 2] + o1[2]) * inv;
        float f3 = (oa[db][rq * 4 + 3] + o1[3]) * inv;
        u32x2 w = (u32x2){pack_bf16(f0, f1), pack_bf16(f2, f3)};
        *(u32x2*)(TR + wq * 4096 + l31 * 128 + ((db * 64 + rq * 16 + hi * 8) ^ kswz)) = w;
      }
  }
  __syncthreads();
#pragma unroll
  for (int c = 0; c < 2; ++c) {
    int ch = c * 256 + tid, q = ch >> 3, sl = ch & 7;
    u32x4 vv = *(const u32x4*)(TR + ((q >> 5) * 4096 + (q & 31) * 128 + ((sl ^ (q & 7)) * 16)));
    *(u32x4*)(ctx + ((size_t)(b * S_) + qi * 64 + q) * H_ + h * HD_ + sl * 8) = vv;
  }
}

// ---------------- host ----------------
extern "C" void kernel_launch(void* const* d_in, const int* in_sizes, int n_in,
                              void* d_out, int out_size, void* d_ws, size_t ws_size,
                              hipStream_t stream) {
  const float* hs   = (const float*)d_in[0];
  const float* am   = (const float*)d_in[1];
  const float* swm  = (const float*)d_in[2];
  const int*   pid  = (const int*)d_in[3];
  const float* qkvw = (const float*)d_in[4];
  const float* ow   = (const float*)d_in[5];
  const float* anw  = (const float*)d_in[6];
  const float* anb  = (const float*)d_in[7];
  const float* mnw  = (const float*)d_in[8];
  const float* mnb  = (const float*)d_in[9];
  const float* wiw  = (const float*)d_in[10];
  const float* wib  = (const float*)d_in[11];
  const float* wow  = (const float*)d_in[12];
  const float* wob  = (const float*)d_in[13];
  float* out = (float*)d_out;

  char* ws = (char*)d_ws;
  size_t off = 0;
  auto alloc = [&](size_t bytes) { void* p = ws + off; off += (bytes + 255) & ~255ull; return p; };

  bf16* wqkv_b = (bf16*)alloc((size_t)3 * H_ * H_ * 2);
  bf16* wo_b   = (bf16*)alloc((size_t)H_ * H_ * 2);
  bf16* wwi_b  = (bf16*)alloc((size_t)2 * I_ * H_ * 2);
  bf16* wwo_b  = (bf16*)alloc((size_t)H_ * I_ * 2);
  bf16* xln    = (bf16*)alloc((size_t)B_ * S_ * H_ * 2);
  bf16* qb     = (bf16*)alloc((size_t)B_ * NH_ * S_ * HD_ * 2);
  bf16* kb     = (bf16*)alloc((size_t)B_ * NH_ * S_ * HD_ * 2);
  bf16* vb     = (bf16*)alloc((size_t)B_ * NH_ * S_ * HD_ * 2);
  bf16* Eg     = (bf16*)alloc((size_t)B_ * S_ * S_ * 2);
  unsigned* flg= (unsigned*)alloc((size_t)B_ * 16 * 32 * 4);
  bf16* ctx    = (bf16*)alloc((size_t)B_ * S_ * H_ * 2);
  float* hid2  = (float*)alloc((size_t)B_ * S_ * H_ * 4);
  bf16* gated  = (bf16*)alloc((size_t)B_ * S_ * I_ * 2);
  f32x2* tbl   = (f32x2*)alloc((size_t)8192 * 32 * 8);
  (void)ws_size; (void)n_in; (void)in_sizes; (void)out_size;

  const int rows = B_ * S_;   // 4096

  prep<<<MASK_BLKS + CVT_BLKS + ROPE_BLKS + LN_BLKS, 256, 0, stream>>>(
      am, swm, Eg, flg,
      qkvw, ow, wiw, wow, wqkv_b, wo_b, wwi_b, wwo_b, tbl, hs, anw, anb, xln);
  gemm_qkv64<<<dim3(3 * H_ / 128, rows / 64), 256, 0, stream>>>(
      xln, wqkv_b, pid, tbl, qb, kb, vb);
  attn4L<<<dim3(S_ / 64, NH_, B_), 256, 0, stream>>>(qb, kb, vb, Eg, flg, ctx);
  gemm64k<false, true><<<dim3(H_ / 128, rows / 64), 256, 0, stream>>>(
      ctx, wo_b, hid2, nullptr, hs, rows, H_, H_);
  ln_bf16<<<rows, 256, 0, stream>>>(hid2, mnw, mnb, xln);
  gemm_wi64<<<dim3(2 * I_ / 128, rows / 64), 256, 0, stream>>>(xln, wwi_b, wib, gated);
  gemm64k<true, true><<<dim3(H_ / 128, rows / 64), 256, 0, stream>>>(
      gated, wwo_b, out, wob, hid2, rows, H_, I_);
}